// Round 4
// baseline (38.096 us; speedup 1.0000x reference)
//
#include <hip/hip_runtime.h>

#define NSEG 4096

// ---------- Kernel 0: bounds[s] = lower_bound(seg, s), s in [0, NSEG] ----------
// seg is sorted ascending. Every entry of bounds[0..NSEG] is written every call
// (deterministic, no zero-init needed).
__global__ __launch_bounds__(256) void scatter_bounds_kernel(
    const int* __restrict__ seg, int* __restrict__ bounds, int nrows)
{
    const int i = blockIdx.x * 256 + threadIdx.x;
    if (i >= nrows) return;
    const int cur  = seg[i];
    const int prev = (i == 0) ? -1 : seg[i - 1];
    for (int s = prev + 1; s <= cur; ++s) bounds[s] = i;
    if (i == nrows - 1) {
        for (int s = cur + 1; s <= NSEG; ++s) bounds[s] = nrows;
    }
}

// ---------- Kernel 1: fused pool + projection ----------
// 2048 blocks x 256 threads (4 waves). Block b owns segment s = b.
//   wave 0: emb_a rows [start,mid)   wave 1: emb_b rows [start,mid)
//   wave 2: emb_a rows [mid,end)     wave 3: emb_b rows [mid,end)
// Raw sums -> LDS (4 quadrants), combine+scale in registers, then wave w
// computes j in [8w, 8w+8) with W rows read coalesced along lanes.
__global__ __launch_bounds__(256, 4) void fused_pool_proj_kernel(
    const float* __restrict__ emb_a,
    const float* __restrict__ emb_b,
    const int*   __restrict__ bounds,  // [NSEG+1]
    const float* __restrict__ W,       // [32][512]
    const float* __restrict__ bias,    // [32]
    float*       __restrict__ out)     // [NSEG][32]
{
    const int s    = blockIdx.x;
    const int t    = threadIdx.x;
    const int wave = t >> 6;
    const int lane = t & 63;

    __shared__ float pooled[1024];   // [4 waves][256 cols]
    __shared__ float sh_out[32];

    const int start = bounds[s];
    const int end   = bounds[s + 1];
    const int cnt   = end - start;
    const int mid   = start + (cnt >> 1);

    const int r0 = (wave >> 1) ? mid : start;
    const int r1 = (wave >> 1) ? end : mid;

    // ---- Phase 1: raw-sum pooling (each wave: its half-range, its emb) ----
    const float*  base = (wave & 1) ? emb_b : emb_a;
    const float4* src  = reinterpret_cast<const float4*>(base) + lane; // row stride 64 float4

    float4 a0 = make_float4(0.f,0.f,0.f,0.f);
    float4 a1 = make_float4(0.f,0.f,0.f,0.f);
    float4 a2 = make_float4(0.f,0.f,0.f,0.f);
    float4 a3 = make_float4(0.f,0.f,0.f,0.f);

    int r = r0;
    for (; r + 4 <= r1; r += 4) {
        float4 v0 = src[(size_t)(r + 0) * 64];
        float4 v1 = src[(size_t)(r + 1) * 64];
        float4 v2 = src[(size_t)(r + 2) * 64];
        float4 v3 = src[(size_t)(r + 3) * 64];
        a0.x += v0.x; a0.y += v0.y; a0.z += v0.z; a0.w += v0.w;
        a1.x += v1.x; a1.y += v1.y; a1.z += v1.z; a1.w += v1.w;
        a2.x += v2.x; a2.y += v2.y; a2.z += v2.z; a2.w += v2.w;
        a3.x += v3.x; a3.y += v3.y; a3.z += v3.z; a3.w += v3.w;
    }
    for (; r < r1; ++r) {
        float4 v = src[(size_t)r * 64];
        a0.x += v.x; a0.y += v.y; a0.z += v.z; a0.w += v.w;
    }

    float4 acc;
    acc.x = a0.x + a1.x + a2.x + a3.x;
    acc.y = a0.y + a1.y + a2.y + a3.y;
    acc.z = a0.z + a1.z + a2.z + a3.z;
    acc.w = a0.w + a1.w + a2.w + a3.w;

    // Quadrant layout: wave w -> pooled[256*w + 4*lane .. +4)
    *reinterpret_cast<float4*>(pooled + (wave << 8) + (lane << 2)) = acc;
    __syncthreads();

    // ---- Combine halves + scale ----
    const float inv = 1.0f / (float)max(cnt, 1);
    const float4* pool4 = reinterpret_cast<const float4*>(pooled);
    const float4 qa0 = pool4[lane];         // emb_a, first half
    const float4 qa1 = pool4[128 + lane];   // emb_a, second half
    const float4 qb0 = pool4[64 + lane];    // emb_b, first half
    const float4 qb1 = pool4[192 + lane];   // emb_b, second half
    float4 p0, p1;
    p0.x = (qa0.x + qa1.x) * inv;  p0.y = (qa0.y + qa1.y) * inv;
    p0.z = (qa0.z + qa1.z) * inv;  p0.w = (qa0.w + qa1.w) * inv;
    p1.x = (qb0.x + qb1.x) * inv;  p1.y = (qb0.y + qb1.y) * inv;
    p1.z = (qb0.z + qb1.z) * inv;  p1.w = (qb0.w + qb1.w) * inv;

    // ---- Phase 2: projection, wave w owns j in [8w, 8w+8) ----
    #pragma unroll 4
    for (int jj = 0; jj < 8; ++jj) {
        const int j = (wave << 3) + jj;
        const float4* wrow = reinterpret_cast<const float4*>(W + j * 512);
        const float4  w0 = wrow[lane];        // 1KB contiguous wave-load (d 0..255)
        const float4  w1 = wrow[64 + lane];   // d 256..511
        float v = p0.x*w0.x + p0.y*w0.y + p0.z*w0.z + p0.w*w0.w
                + p1.x*w1.x + p1.y*w1.y + p1.z*w1.z + p1.w*w1.w;
        v += __shfl_xor(v, 1);
        v += __shfl_xor(v, 2);
        v += __shfl_xor(v, 4);
        v += __shfl_xor(v, 8);
        v += __shfl_xor(v, 16);
        v += __shfl_xor(v, 32);
        if (lane == 0) sh_out[j] = v + bias[j];
    }
    __syncthreads();

    if (t < 32) out[s * 32 + t] = sh_out[t];
}

// ---------- Fallback (ws too small): round-3 fused kernel with binary search ----------
__global__ __launch_bounds__(128, 8) void fused_fallback_kernel(
    const float* __restrict__ emb_a,
    const float* __restrict__ emb_b,
    const int*   __restrict__ seg,
    const float* __restrict__ W,
    const float* __restrict__ bias,
    float*       __restrict__ out,
    int nrows)
{
    const int s = blockIdx.x;
    const int t = threadIdx.x;
    const int wave = t >> 6;
    const int lane = t & 63;
    __shared__ int   bounds[2];
    __shared__ float pooled[512];
    __shared__ float sh_out[32];
    if (t < 2) {
        int target = s + t;
        int lo = 0, hi = nrows;
        while (lo < hi) { int mid = (lo + hi) >> 1; if (seg[mid] < target) lo = mid + 1; else hi = mid; }
        bounds[t] = lo;
    }
    __syncthreads();
    const int start = bounds[0], end = bounds[1];
    const int cnt = end - start;
    const float*  base = (wave == 0) ? emb_a : emb_b;
    const float4* src  = reinterpret_cast<const float4*>(base) + lane;
    float4 a0 = make_float4(0.f,0.f,0.f,0.f);
    float4 a1 = make_float4(0.f,0.f,0.f,0.f);
    float4 a2 = make_float4(0.f,0.f,0.f,0.f);
    float4 a3 = make_float4(0.f,0.f,0.f,0.f);
    int r = start;
    for (; r + 4 <= end; r += 4) {
        float4 v0 = src[(size_t)(r + 0) * 64];
        float4 v1 = src[(size_t)(r + 1) * 64];
        float4 v2 = src[(size_t)(r + 2) * 64];
        float4 v3 = src[(size_t)(r + 3) * 64];
        a0.x += v0.x; a0.y += v0.y; a0.z += v0.z; a0.w += v0.w;
        a1.x += v1.x; a1.y += v1.y; a1.z += v1.z; a1.w += v1.w;
        a2.x += v2.x; a2.y += v2.y; a2.z += v2.z; a2.w += v2.w;
        a3.x += v3.x; a3.y += v3.y; a3.z += v3.z; a3.w += v3.w;
    }
    for (; r < end; ++r) {
        float4 v = src[(size_t)r * 64];
        a0.x += v.x; a0.y += v.y; a0.z += v.z; a0.w += v.w;
    }
    const float inv = 1.0f / (float)max(cnt, 1);
    float4 acc;
    acc.x = (a0.x + a1.x + a2.x + a3.x) * inv;
    acc.y = (a0.y + a1.y + a2.y + a3.y) * inv;
    acc.z = (a0.z + a1.z + a2.z + a3.z) * inv;
    acc.w = (a0.w + a1.w + a2.w + a3.w) * inv;
    *reinterpret_cast<float4*>(pooled + (wave << 8) + (lane << 2)) = acc;
    __syncthreads();
    const float4* pool4 = reinterpret_cast<const float4*>(pooled);
    const float4  p0 = pool4[lane];
    const float4  p1 = pool4[64 + lane];
    #pragma unroll 4
    for (int jj = 0; jj < 16; ++jj) {
        const int j = (wave << 4) + jj;
        const float4* wrow = reinterpret_cast<const float4*>(W + j * 512);
        const float4  w0 = wrow[lane];
        const float4  w1 = wrow[64 + lane];
        float v = p0.x*w0.x + p0.y*w0.y + p0.z*w0.z + p0.w*w0.w
                + p1.x*w1.x + p1.y*w1.y + p1.z*w1.z + p1.w*w1.w;
        v += __shfl_xor(v, 1);
        v += __shfl_xor(v, 2);
        v += __shfl_xor(v, 4);
        v += __shfl_xor(v, 8);
        v += __shfl_xor(v, 16);
        v += __shfl_xor(v, 32);
        if (lane == 0) sh_out[j] = v + bias[j];
    }
    __syncthreads();
    if (t < 32) out[s * 32 + t] = sh_out[t];
}

extern "C" void kernel_launch(void* const* d_in, const int* in_sizes, int n_in,
                              void* d_out, int out_size, void* d_ws, size_t ws_size,
                              hipStream_t stream) {
    const float* emb_a = (const float*)d_in[0];
    const float* emb_b = (const float*)d_in[1];
    const int*   seg   = (const int*)d_in[2];
    const float* W     = (const float*)d_in[3];
    const float* bias  = (const float*)d_in[4];
    float*       out   = (float*)d_out;
    const int nrows = in_sizes[2];

    const size_t need = (size_t)(NSEG + 1) * sizeof(int);
    if (ws_size >= need) {
        int* bounds = (int*)d_ws;
        scatter_bounds_kernel<<<(nrows + 255) / 256, 256, 0, stream>>>(seg, bounds, nrows);
        fused_pool_proj_kernel<<<NSEG, 256, 0, stream>>>(emb_a, emb_b, bounds, W, bias, out);
    } else {
        fused_fallback_kernel<<<NSEG, 128, 0, stream>>>(emb_a, emb_b, seg, W, bias, out, nrows);
    }
}